// Round 2
// baseline (261.569 us; speedup 1.0000x reference)
//
#include <hip/hip_runtime.h>
#include <hip/hip_bf16.h>

#define NPTS   131072
#define NNODES 2048
#define KSEL   32
#define T1     256
#define B1     (NPTS / T1)   // 512 blocks

typedef unsigned int uint;

// --- K0: pack nodes as float4 {x,y,z,|n|^2}, |n|^2 with numpy's mul-then-add rounding ---
__global__ __launch_bounds__(256) void prep_nodes(const float* __restrict__ nodes,
                                                  float4* __restrict__ n4) {
    int j = blockIdx.x * blockDim.x + threadIdx.x;
    if (j < NNODES) {
        float x = nodes[3 * j], y = nodes[3 * j + 1], z = nodes[3 * j + 2];
        float nn = __fadd_rn(__fadd_rn(__fmul_rn(x, x), __fmul_rn(y, y)), __fmul_rn(z, z));
        n4[j] = make_float4(x, y, z, nn);
    }
}

// --- K1: brute-force 1-NN (replicating ref fp32 rounding) + per-block histogram ---
__global__ __launch_bounds__(256) void knn_hist(const float* __restrict__ pts,
                                                const float4* __restrict__ n4,
                                                float* __restrict__ out_d2,
                                                float* __restrict__ out_id,
                                                int* __restrict__ pcd,
                                                uint* __restrict__ hist) {
    __shared__ uint lh[NNODES];
    int tid = threadIdx.x;
    for (int i = tid; i < NNODES; i += T1) lh[i] = 0;
    __syncthreads();

    int pid = blockIdx.x * T1 + tid;
    float p0 = pts[3 * pid], p1 = pts[3 * pid + 1], p2 = pts[3 * pid + 2];
    // pp = (p0*p0 + p1*p1) + p2*p2, no fma (numpy sum of products)
    float pp = __fadd_rn(__fadd_rn(__fmul_rn(p0, p0), __fmul_rn(p1, p1)), __fmul_rn(p2, p2));

    float best = 3.4e38f;
    int bidx = 0;
    #pragma unroll 4
    for (int j = 0; j < NNODES; ++j) {
        float4 v = n4[j];   // wave-uniform address -> expect s_load batching
        // BLAS K=3 dot: fma chain ascending k, first term plain product
        float dot = __fmaf_rn(p2, v.z, __fmaf_rn(p1, v.y, __fmul_rn(p0, v.x)));
        // ref: (pp - 2*dot) + nn, elementwise fp32
        float d2 = __fadd_rn(__fsub_rn(pp, __fmul_rn(2.0f, dot)), v.w);
        if (d2 < best) { best = d2; bidx = j; }   // strict < keeps first index on ties
    }

    atomicAdd(&lh[bidx], 1u);
    out_d2[pid] = best;
    out_id[pid] = (float)bidx;          // exact: bidx < 2^24
    pcd[pid]    = bidx;

    __syncthreads();
    for (int i = tid; i < NNODES; i += T1)
        hist[(size_t)blockIdx.x * NNODES + i] = lh[i];
}

// --- K2: per-node exclusive prefix over the 512 block-histograms ---
// grid = NNODES/8 blocks of 512 threads; thread t handles source-block index t.
__global__ __launch_bounds__(512) void scan_hist(uint* __restrict__ hist) {
    int t = threadIdx.x;            // b in [0,512)
    int lane = t & 63, wv = t >> 6; // 8 waves
    __shared__ uint partial[8];
    for (int k = 0; k < 8; ++k) {
        int node = blockIdx.x * 8 + k;
        uint v = hist[(size_t)t * NNODES + node];
        uint s = v;
        #pragma unroll
        for (int d = 1; d < 64; d <<= 1) {
            uint y = __shfl_up(s, d, 64);
            if (lane >= d) s += y;
        }
        if (lane == 63) partial[wv] = s;
        __syncthreads();
        uint off = 0;
        for (int w = 0; w < wv; ++w) off += partial[w];
        hist[(size_t)t * NNODES + node] = s + off - v;  // exclusive prefix
        __syncthreads();
    }
}

// --- K3: stable scatter of first-32 point indices per node ---
__global__ __launch_bounds__(256) void scatter_patch(const int* __restrict__ pcd,
                                                     const uint* __restrict__ hist,
                                                     float* __restrict__ patch) {
    __shared__ int ids[T1];
    int tid = threadIdx.x;
    int pid = blockIdx.x * T1 + tid;
    int myid = pcd[pid];
    ids[tid] = myid;
    __syncthreads();
    int r = 0;
    #pragma unroll 8
    for (int j = 0; j < T1; ++j) {
        // uniform-address LDS broadcast read, no bank conflicts
        r += (j < tid && ids[j] == myid) ? 1 : 0;
    }
    uint rank = hist[(size_t)blockIdx.x * NNODES + myid] + (uint)r;
    if (rank < KSEL)
        patch[(size_t)myid * KSEL + rank] = (float)pid;   // exact: pid < 2^24
}

extern "C" void kernel_launch(void* const* d_in, const int* in_sizes, int n_in,
                              void* d_out, int out_size, void* d_ws, size_t ws_size,
                              hipStream_t stream) {
    const float* pts   = (const float*)d_in[0];
    const float* nodes = (const float*)d_in[1];

    float* out       = (float*)d_out;
    float* out_d2    = out;                 // 131072 floats
    float* out_id    = out + NPTS;          // 131072 floats
    float* out_patch = out + 2 * NPTS;      // 65536 floats

    char* ws = (char*)d_ws;
    float4* n4  = (float4*)ws;                        // 32 KB
    int*    pcd = (int*)(ws + 32768);                 // 512 KB
    uint*   hist = (uint*)(ws + 32768 + 524288);      // 4 MB (512 x 2048 u32)

    // patch defaults to 0 (ref: maximum(patch, 0))
    hipMemsetAsync(out_patch, 0, (size_t)NNODES * KSEL * sizeof(float), stream);

    prep_nodes<<<(NNODES + 255) / 256, 256, 0, stream>>>(nodes, n4);
    knn_hist<<<B1, T1, 0, stream>>>(pts, n4, out_d2, out_id, pcd, hist);
    scan_hist<<<NNODES / 8, 512, 0, stream>>>(hist);
    scatter_patch<<<B1, T1, 0, stream>>>(pcd, hist, out_patch);
}

// Round 3
// 203.874 us; speedup vs baseline: 1.2830x; 1.2830x over previous
//
#include <hip/hip_runtime.h>
#include <hip/hip_bf16.h>

#define NPTS   131072
#define NNODES 2048
#define KSEL   32
#define TPB    1024          // threads per knn block
#define PPB    256           // points per knn block
#define NCHUNK 4             // node-dim split
#define CHN    (NNODES / NCHUNK)   // 512 nodes per chunk
#define B1     (NPTS / PPB)  // 512 blocks

typedef unsigned int uint;

// --- K0: pack nodes as float4 {x,y,z,|n|^2}, |n|^2 with numpy's mul-then-add rounding ---
__global__ __launch_bounds__(256) void prep_nodes(const float* __restrict__ nodes,
                                                  float4* __restrict__ n4) {
    int j = blockIdx.x * blockDim.x + threadIdx.x;
    if (j < NNODES) {
        float x = nodes[3 * j], y = nodes[3 * j + 1], z = nodes[3 * j + 2];
        float nn = __fadd_rn(__fadd_rn(__fmul_rn(x, x), __fmul_rn(y, y)), __fmul_rn(z, z));
        n4[j] = make_float4(x, y, z, nn);
    }
}

// --- K1: brute-force 1-NN, node-dim split 4-way per block for occupancy ---
__global__ __launch_bounds__(1024) void knn_hist(const float* __restrict__ pts,
                                                 const float4* __restrict__ n4,
                                                 float* __restrict__ out_d2,
                                                 float* __restrict__ out_id,
                                                 int* __restrict__ pcd,
                                                 uint* __restrict__ hist) {
    __shared__ uint  lh[NNODES];
    __shared__ float sbest[NCHUNK][PPB];
    __shared__ int   sidx[NCHUNK][PPB];

    int t = threadIdx.x;
    for (int i = t; i < NNODES; i += TPB) lh[i] = 0;

    int p   = t & (PPB - 1);      // point lane within block
    int c   = t >> 8;             // node chunk 0..3
    int pid = blockIdx.x * PPB + p;

    float p0 = pts[3 * pid], p1 = pts[3 * pid + 1], p2 = pts[3 * pid + 2];
    // pp = (p0*p0 + p1*p1) + p2*p2, no fma (numpy sum-of-products rounding)
    float pp = __fadd_rn(__fadd_rn(__fmul_rn(p0, p0), __fmul_rn(p1, p1)), __fmul_rn(p2, p2));

    int   j0   = c * CHN;
    float best = 3.4e38f;
    int   bidx = j0;
    #pragma unroll 8
    for (int jj = 0; jj < CHN; ++jj) {
        int j = j0 + jj;
        float4 v = n4[j];   // wave-uniform address -> scalar (SMEM) loads
        // BLAS K=3 dot: fma chain ascending k, first term plain product
        float dot = __fmaf_rn(p2, v.z, __fmaf_rn(p1, v.y, __fmul_rn(p0, v.x)));
        // ref: (pp - 2*dot) + nn, elementwise fp32
        float d2 = __fadd_rn(__fsub_rn(pp, __fmul_rn(2.0f, dot)), v.w);
        if (d2 < best) { best = d2; bidx = j; }   // strict <: first occurrence wins
    }
    sbest[c][p] = best;
    sidx [c][p] = bidx;
    __syncthreads();

    if (t < PPB) {
        float b  = sbest[0][t];
        int   bi = sidx [0][t];
        #pragma unroll
        for (int cc = 1; cc < NCHUNK; ++cc) {
            float v = sbest[cc][t];
            if (v < b) { b = v; bi = sidx[cc][t]; }  // strict <: earlier chunk wins ties
        }
        int mypid = blockIdx.x * PPB + t;
        atomicAdd(&lh[bi], 1u);
        out_d2[mypid] = b;
        out_id[mypid] = (float)bi;     // exact: bi < 2^24
        pcd[mypid]    = bi;
    }
    __syncthreads();

    for (int i = t; i < NNODES; i += TPB)
        hist[(size_t)blockIdx.x * NNODES + i] = lh[i];
}

// --- K2: per-node exclusive prefix over the 512 block-histograms ---
__global__ __launch_bounds__(512) void scan_hist(uint* __restrict__ hist) {
    int t = threadIdx.x;            // source-block index b in [0,512)
    int lane = t & 63, wv = t >> 6; // 8 waves
    __shared__ uint partial[8];
    for (int k = 0; k < 8; ++k) {
        int node = blockIdx.x * 8 + k;
        uint v = hist[(size_t)t * NNODES + node];
        uint s = v;
        #pragma unroll
        for (int d = 1; d < 64; d <<= 1) {
            uint y = __shfl_up(s, d, 64);
            if (lane >= d) s += y;
        }
        if (lane == 63) partial[wv] = s;
        __syncthreads();
        uint off = 0;
        for (int w = 0; w < wv; ++w) off += partial[w];
        hist[(size_t)t * NNODES + node] = s + off - v;  // exclusive prefix
        __syncthreads();
    }
}

// --- K3: stable scatter of first-32 point indices per node ---
__global__ __launch_bounds__(256) void scatter_patch(const int* __restrict__ pcd,
                                                     const uint* __restrict__ hist,
                                                     float* __restrict__ patch) {
    __shared__ int ids[PPB];
    int tid = threadIdx.x;
    int pid = blockIdx.x * PPB + tid;
    int myid = pcd[pid];
    ids[tid] = myid;
    __syncthreads();
    int r = 0;
    #pragma unroll 8
    for (int j = 0; j < PPB; ++j) {
        // uniform-address LDS broadcast read, no bank conflicts
        r += (j < tid && ids[j] == myid) ? 1 : 0;
    }
    uint rank = hist[(size_t)blockIdx.x * NNODES + myid] + (uint)r;
    if (rank < KSEL)
        patch[(size_t)myid * KSEL + rank] = (float)pid;   // exact: pid < 2^24
}

extern "C" void kernel_launch(void* const* d_in, const int* in_sizes, int n_in,
                              void* d_out, int out_size, void* d_ws, size_t ws_size,
                              hipStream_t stream) {
    const float* pts   = (const float*)d_in[0];
    const float* nodes = (const float*)d_in[1];

    float* out       = (float*)d_out;
    float* out_d2    = out;                 // 131072 floats
    float* out_id    = out + NPTS;          // 131072 floats
    float* out_patch = out + 2 * NPTS;      // 65536 floats

    char* ws = (char*)d_ws;
    float4* n4  = (float4*)ws;                        // 32 KB
    int*    pcd = (int*)(ws + 32768);                 // 512 KB
    uint*   hist = (uint*)(ws + 32768 + 524288);      // 4 MB (512 x 2048 u32)

    // patch defaults to 0 (ref: maximum(patch, 0))
    hipMemsetAsync(out_patch, 0, (size_t)NNODES * KSEL * sizeof(float), stream);

    prep_nodes<<<(NNODES + 255) / 256, 256, 0, stream>>>(nodes, n4);
    knn_hist<<<B1, TPB, 0, stream>>>(pts, n4, out_d2, out_id, pcd, hist);
    scan_hist<<<NNODES / 8, 512, 0, stream>>>(hist);
    scatter_patch<<<NPTS / PPB, PPB, 0, stream>>>(pcd, hist, out_patch);
}

// Round 4
// 150.914 us; speedup vs baseline: 1.7332x; 1.3509x over previous
//
#include <hip/hip_runtime.h>
#include <hip/hip_bf16.h>

#define NPTS   131072
#define NNODES 2048
#define KSEL   32
#define PPB    256                 // points per group
#define NGRP   (NPTS / PPB)        // 512 point groups
#define NCHUNK 4                   // node-dim split (by blockIdx -> scalar loads)
#define CHN    (NNODES / NCHUNK)   // 512 nodes per chunk

typedef unsigned int uint;

// --- K0: pack nodes as float4 {x,y,z,|n|^2}, |n|^2 with numpy's mul-then-add rounding ---
__global__ __launch_bounds__(256) void prep_nodes(const float* __restrict__ nodes,
                                                  float4* __restrict__ n4) {
    int j = blockIdx.x * blockDim.x + threadIdx.x;
    if (j < NNODES) {
        float x = nodes[3 * j], y = nodes[3 * j + 1], z = nodes[3 * j + 2];
        float nn = __fadd_rn(__fadd_rn(__fmul_rn(x, x), __fmul_rn(y, y)), __fmul_rn(z, z));
        n4[j] = make_float4(x, y, z, nn);
    }
}

// --- K1: partial 1-NN over one node chunk; chunk id from blockIdx -> scalar s_load ---
__global__ __launch_bounds__(256) void knn_part(const float* __restrict__ pts,
                                                const float4* __restrict__ n4,
                                                float* __restrict__ pbest,
                                                int* __restrict__ pidx) {
    int bid = blockIdx.x;
    int c   = bid & (NCHUNK - 1);     // block-uniform chunk
    int g   = bid >> 2;               // point group
    int pid = g * PPB + threadIdx.x;

    float p0 = pts[3 * pid], p1 = pts[3 * pid + 1], p2 = pts[3 * pid + 2];
    // pp = (p0*p0 + p1*p1) + p2*p2, no fma (numpy sum-of-products rounding)
    float pp = __fadd_rn(__fadd_rn(__fmul_rn(p0, p0), __fmul_rn(p1, p1)), __fmul_rn(p2, p2));

    const float4* np = n4 + c * CHN;  // block-uniform base
    float best = 3.4e38f;
    int   bidx = c * CHN;
    #pragma unroll 8
    for (int jj = 0; jj < CHN; ++jj) {
        float4 v = np[jj];            // uniform address -> s_load batching
        // BLAS K=3 dot: fma chain ascending k, first term plain product
        float dot = __fmaf_rn(p2, v.z, __fmaf_rn(p1, v.y, __fmul_rn(p0, v.x)));
        // ref: (pp - 2*dot) + nn, elementwise fp32
        float d2 = __fadd_rn(__fsub_rn(pp, __fmul_rn(2.0f, dot)), v.w);
        if (d2 < best) { best = d2; bidx = c * CHN + jj; }  // strict <: first wins
    }
    pbest[(size_t)c * NPTS + pid] = best;   // coalesced
    pidx [(size_t)c * NPTS + pid] = bidx;
}

// --- K2: merge 4 chunk-partials per point + per-group histogram ---
__global__ __launch_bounds__(256) void merge_hist(const float* __restrict__ pbest,
                                                  const int* __restrict__ pidx,
                                                  float* __restrict__ out_d2,
                                                  float* __restrict__ out_id,
                                                  int* __restrict__ pcd,
                                                  uint* __restrict__ hist) {
    __shared__ uint lh[NNODES];
    int t = threadIdx.x;
    for (int i = t; i < NNODES; i += PPB) lh[i] = 0;
    __syncthreads();

    int pid = blockIdx.x * PPB + t;
    float b  = pbest[pid];
    int   bi = pidx[pid];
    #pragma unroll
    for (int c = 1; c < NCHUNK; ++c) {
        float v = pbest[(size_t)c * NPTS + pid];
        int   i = pidx [(size_t)c * NPTS + pid];
        if (v < b) { b = v; bi = i; }   // strict <: earlier chunk wins ties
    }
    atomicAdd(&lh[bi], 1u);
    out_d2[pid] = b;
    out_id[pid] = (float)bi;            // exact: bi < 2^24
    pcd[pid]    = bi;

    __syncthreads();
    for (int i = t; i < NNODES; i += PPB)
        hist[(size_t)blockIdx.x * NNODES + i] = lh[i];
}

// --- K3: per-node exclusive prefix over the 512 group-histograms ---
// 64 blocks x 512 threads; block covers 32 consecutive nodes; thread t = source group.
// Each thread loads 32 contiguous uints (128 B) -> full cache-line utilization.
__global__ __launch_bounds__(512) void scan_hist(uint* __restrict__ hist) {
    __shared__ uint partial[32][8];
    int t = threadIdx.x, lane = t & 63, wv = t >> 6;   // 8 waves
    int n0 = blockIdx.x * 32;

    uint4* row = (uint4*)(hist + (size_t)t * NNODES + n0);
    uint v[32];
    #pragma unroll
    for (int q = 0; q < 8; ++q) {
        uint4 x = row[q];
        v[4*q] = x.x; v[4*q+1] = x.y; v[4*q+2] = x.z; v[4*q+3] = x.w;
    }

    uint s[32];
    #pragma unroll
    for (int k = 0; k < 32; ++k) {
        uint a = v[k];
        #pragma unroll
        for (int d = 1; d < 64; d <<= 1) {
            uint y = __shfl_up(a, d, 64);
            if (lane >= d) a += y;
        }
        s[k] = a;                       // inclusive within wave
        if (lane == 63) partial[k][wv] = a;
    }
    __syncthreads();
    #pragma unroll
    for (int k = 0; k < 32; ++k) {
        uint off = 0;
        for (int w = 0; w < wv; ++w) off += partial[k][w];
        s[k] = s[k] + off - v[k];       // exclusive across all 512 groups
    }
    #pragma unroll
    for (int q = 0; q < 8; ++q)
        row[q] = make_uint4(s[4*q], s[4*q+1], s[4*q+2], s[4*q+3]);
}

// --- K4: stable scatter of first-32 point indices per node ---
__global__ __launch_bounds__(256) void scatter_patch(const int* __restrict__ pcd,
                                                     const uint* __restrict__ hist,
                                                     float* __restrict__ patch) {
    __shared__ int ids[PPB];
    int tid = threadIdx.x;
    int pid = blockIdx.x * PPB + tid;
    int myid = pcd[pid];
    ids[tid] = myid;
    __syncthreads();
    int r = 0;
    #pragma unroll 8
    for (int j = 0; j < PPB; ++j) {
        // uniform-address LDS broadcast read, no bank conflicts
        r += (j < tid && ids[j] == myid) ? 1 : 0;
    }
    uint rank = hist[(size_t)blockIdx.x * NNODES + myid] + (uint)r;
    if (rank < KSEL)
        patch[(size_t)myid * KSEL + rank] = (float)pid;   // exact: pid < 2^24
}

extern "C" void kernel_launch(void* const* d_in, const int* in_sizes, int n_in,
                              void* d_out, int out_size, void* d_ws, size_t ws_size,
                              hipStream_t stream) {
    const float* pts   = (const float*)d_in[0];
    const float* nodes = (const float*)d_in[1];

    float* out       = (float*)d_out;
    float* out_d2    = out;                 // 131072 floats
    float* out_id    = out + NPTS;          // 131072 floats
    float* out_patch = out + 2 * NPTS;      // 65536 floats

    char* ws = (char*)d_ws;
    float4* n4    = (float4*)ws;                                   // 32 KB
    int*    pcd   = (int*)  (ws + (32 << 10));                     // 512 KB
    uint*   hist  = (uint*) (ws + (32 << 10) + (512 << 10));       // 4 MB
    float*  pbest = (float*)(ws + (32 << 10) + (512 << 10) + (4 << 20));          // 2 MB
    int*    pidx  = (int*)  (ws + (32 << 10) + (512 << 10) + (4 << 20) + (2 << 20)); // 2 MB

    // patch defaults to 0 (ref: maximum(patch, 0))
    hipMemsetAsync(out_patch, 0, (size_t)NNODES * KSEL * sizeof(float), stream);

    prep_nodes<<<(NNODES + 255) / 256, 256, 0, stream>>>(nodes, n4);
    knn_part<<<NGRP * NCHUNK, PPB, 0, stream>>>(pts, n4, pbest, pidx);
    merge_hist<<<NGRP, PPB, 0, stream>>>(pbest, pidx, out_d2, out_id, pcd, hist);
    scan_hist<<<NNODES / 32, 512, 0, stream>>>(hist);
    scatter_patch<<<NGRP, PPB, 0, stream>>>(pcd, hist, out_patch);
}